// Round 8
// baseline (246.523 us; speedup 1.0000x reference)
//
#include <hip/hip_runtime.h>

// Problem constants (match reference)
#define S_LEN 4096
#define DMODEL 1024
#define NH 16
#define DH 64
#define WIN 256
#define NQKV 3072  // fused QKV output width

typedef __attribute__((ext_vector_type(8))) short short8;
typedef __attribute__((ext_vector_type(4))) short sh4;
typedef __attribute__((ext_vector_type(4))) float floatx4;

__device__ __forceinline__ ushort f2bf(float f) {
    union { float f; unsigned int i; } x;
    x.f = f;
    unsigned int r = x.i + 0x7FFFu + ((x.i >> 16) & 1u);  // RNE
    return (ushort)(r >> 16);
}

// ---------------------------------------------------------------------------
// Fused fp32 -> bf16 convert for x, wq, wk, wv, wo in ONE dispatch.
// ---------------------------------------------------------------------------
__global__ __launch_bounds__(256) void cvt_all(const float* __restrict__ x,
                                               const float* __restrict__ wq,
                                               const float* __restrict__ wk,
                                               const float* __restrict__ wv,
                                               const float* __restrict__ wo,
                                               ushort* __restrict__ xb,
                                               ushort* __restrict__ W3b,
                                               ushort* __restrict__ wob,
                                               int nx8, int nw8) {
    int i = blockIdx.x * 256 + threadIdx.x;
    const float* src;
    ushort* dst;
    if (i < nx8) {
        src = x + (size_t)i * 8;            dst = xb + (size_t)i * 8;
    } else {
        int j = i - nx8;
        int which = j / nw8, r = j - which * nw8;
        if (which >= 4) return;
        const float* w4[4] = {wq, wk, wv, wo};
        src = w4[which] + (size_t)r * 8;
        dst = (which == 3 ? wob : W3b + (size_t)which * nw8 * 8) + (size_t)r * 8;
    }
    floatx4 f0 = *(const floatx4*)src;
    floatx4 f1 = *(const floatx4*)(src + 4);
    short8 v;
#pragma unroll
    for (int e = 0; e < 4; ++e) v[e] = (short)f2bf(f0[e]);
#pragma unroll
    for (int e = 0; e < 4; ++e) v[4 + e] = (short)f2bf(f1[e]);
    *(short8*)dst = v;
}

// ---------------------------------------------------------------------------
// bf16 GEMM, 128x128 tile (m97 structure) — used for the output projection.
// ---------------------------------------------------------------------------
template <bool OUTF32>
__global__ __launch_bounds__(256) void gemm_bf16(const ushort* __restrict__ A,
                                                 const ushort* __restrict__ W,
                                                 void* __restrict__ Cout,
                                                 int M, int N, int K) {
    __shared__ __align__(16) ushort As[128 * 32];  // 8 KB
    __shared__ __align__(16) ushort Ws[128 * 32];

    const int tid = threadIdx.x;
    const int w = tid >> 6, l = tid & 63;
    const int bm0 = blockIdx.y * 128, bn0 = blockIdx.x * 128;
    const int wm = (w >> 1) * 64, wn = (w & 1) * 64;
    const int lm = l & 15, quad = l >> 4;

    floatx4 acc[4][4] = {};

    // chunk c = tid (and tid+256): row = c>>2, colseg = c&3
    const int row0 = tid >> 2, col0 = (tid & 3) * 8;
    const ushort* a0 = A + (size_t)(bm0 + row0) * K + col0;
    const ushort* a1 = A + (size_t)(bm0 + row0 + 64) * K + col0;
    const ushort* w0 = W + (size_t)(bn0 + row0) * K + col0;
    const ushort* w1 = W + (size_t)(bn0 + row0 + 64) * K + col0;

    for (int k0 = 0; k0 < K; k0 += 32) {
        __builtin_amdgcn_global_load_lds(
            (const __attribute__((address_space(1))) void*)(a0 + k0),
            (__attribute__((address_space(3))) void*)(As + tid * 8), 16, 0, 0);
        __builtin_amdgcn_global_load_lds(
            (const __attribute__((address_space(1))) void*)(a1 + k0),
            (__attribute__((address_space(3))) void*)(As + 2048 + tid * 8), 16, 0, 0);
        __builtin_amdgcn_global_load_lds(
            (const __attribute__((address_space(1))) void*)(w0 + k0),
            (__attribute__((address_space(3))) void*)(Ws + tid * 8), 16, 0, 0);
        __builtin_amdgcn_global_load_lds(
            (const __attribute__((address_space(1))) void*)(w1 + k0),
            (__attribute__((address_space(3))) void*)(Ws + 2048 + tid * 8), 16, 0, 0);
        __syncthreads();

        short8 af[4], wf[4];
#pragma unroll
        for (int mi = 0; mi < 4; ++mi)
            af[mi] = *(const short8*)&As[(wm + mi * 16 + lm) * 32 + quad * 8];
#pragma unroll
        for (int ni = 0; ni < 4; ++ni)
            wf[ni] = *(const short8*)&Ws[(wn + ni * 16 + lm) * 32 + quad * 8];
#pragma unroll
        for (int mi = 0; mi < 4; ++mi)
#pragma unroll
            for (int ni = 0; ni < 4; ++ni)
                acc[mi][ni] = __builtin_amdgcn_mfma_f32_16x16x32_bf16(
                    af[mi], wf[ni], acc[mi][ni], 0, 0, 0);
        __syncthreads();
    }

#pragma unroll
    for (int mi = 0; mi < 4; ++mi)
#pragma unroll
        for (int ni = 0; ni < 4; ++ni)
#pragma unroll
            for (int r = 0; r < 4; ++r) {
                int row = bm0 + wm + mi * 16 + quad * 4 + r;
                int col = bn0 + wn + ni * 16 + lm;
                if (OUTF32)
                    ((float*)Cout)[(size_t)row * N + col] = acc[mi][ni][r];
                else
                    ((ushort*)Cout)[(size_t)row * N + col] = f2bf(acc[mi][ni][r]);
            }
}

// ---------------------------------------------------------------------------
// bf16 GEMM, 128x256 block / 64x128 wave tile — used for the QKV projection.
// Wider wave tile: 32 MFMA per 12 frag-reads = 42.7 FLOP per LDS byte
// (vs 32 for the 64x64 tile) — attacks the LDS-read-bandwidth bound.
// ---------------------------------------------------------------------------
template <bool OUTF32>
__global__ __launch_bounds__(256, 2) void gemm_wide(const ushort* __restrict__ A,
                                                    const ushort* __restrict__ W,
                                                    void* __restrict__ Cout,
                                                    int M, int N, int K) {
    __shared__ __align__(16) ushort As[128 * 32];  // 8 KB
    __shared__ __align__(16) ushort Ws[256 * 32];  // 16 KB

    const int tid = threadIdx.x;
    const int w = tid >> 6, l = tid & 63;
    const int bm0 = blockIdx.y * 128, bn0 = blockIdx.x * 256;
    const int wm = (w >> 1) * 64, wn = (w & 1) * 128;
    const int lm = l & 15, quad = l >> 4;

    floatx4 acc[4][8] = {};

    const int row0 = tid >> 2, col0 = (tid & 3) * 8;
    const ushort* a0 = A + (size_t)(bm0 + row0) * K + col0;
    const ushort* a1 = A + (size_t)(bm0 + row0 + 64) * K + col0;
    const ushort* wp0 = W + (size_t)(bn0 + row0) * K + col0;
    const ushort* wp1 = W + (size_t)(bn0 + row0 + 64) * K + col0;
    const ushort* wp2 = W + (size_t)(bn0 + row0 + 128) * K + col0;
    const ushort* wp3 = W + (size_t)(bn0 + row0 + 192) * K + col0;

    for (int k0 = 0; k0 < K; k0 += 32) {
        __builtin_amdgcn_global_load_lds(
            (const __attribute__((address_space(1))) void*)(a0 + k0),
            (__attribute__((address_space(3))) void*)(As + tid * 8), 16, 0, 0);
        __builtin_amdgcn_global_load_lds(
            (const __attribute__((address_space(1))) void*)(a1 + k0),
            (__attribute__((address_space(3))) void*)(As + 2048 + tid * 8), 16, 0, 0);
        __builtin_amdgcn_global_load_lds(
            (const __attribute__((address_space(1))) void*)(wp0 + k0),
            (__attribute__((address_space(3))) void*)(Ws + tid * 8), 16, 0, 0);
        __builtin_amdgcn_global_load_lds(
            (const __attribute__((address_space(1))) void*)(wp1 + k0),
            (__attribute__((address_space(3))) void*)(Ws + 2048 + tid * 8), 16, 0, 0);
        __builtin_amdgcn_global_load_lds(
            (const __attribute__((address_space(1))) void*)(wp2 + k0),
            (__attribute__((address_space(3))) void*)(Ws + 4096 + tid * 8), 16, 0, 0);
        __builtin_amdgcn_global_load_lds(
            (const __attribute__((address_space(1))) void*)(wp3 + k0),
            (__attribute__((address_space(3))) void*)(Ws + 6144 + tid * 8), 16, 0, 0);
        __syncthreads();

        short8 af[4], wf[8];
#pragma unroll
        for (int mi = 0; mi < 4; ++mi)
            af[mi] = *(const short8*)&As[(wm + mi * 16 + lm) * 32 + quad * 8];
#pragma unroll
        for (int ni = 0; ni < 8; ++ni)
            wf[ni] = *(const short8*)&Ws[(wn + ni * 16 + lm) * 32 + quad * 8];
#pragma unroll
        for (int mi = 0; mi < 4; ++mi)
#pragma unroll
            for (int ni = 0; ni < 8; ++ni)
                acc[mi][ni] = __builtin_amdgcn_mfma_f32_16x16x32_bf16(
                    af[mi], wf[ni], acc[mi][ni], 0, 0, 0);
        __syncthreads();
    }

#pragma unroll
    for (int mi = 0; mi < 4; ++mi)
#pragma unroll
        for (int ni = 0; ni < 8; ++ni)
#pragma unroll
            for (int r = 0; r < 4; ++r) {
                int row = bm0 + wm + mi * 16 + quad * 4 + r;
                int col = bn0 + wn + ni * 16 + lm;
                if (OUTF32)
                    ((float*)Cout)[(size_t)row * N + col] = acc[mi][ni][r];
                else
                    ((ushort*)Cout)[(size_t)row * N + col] = f2bf(acc[mi][ni][r]);
            }
}

// ---------------------------------------------------------------------------
// MFMA sliding-window attention over fused QKV layout [M][3072].
// R8 changes: (1) Vt physical-row bit-swap pi(d)=((d&7)<<3)|(d>>3) makes the
// transpose-staging writes conflict-free (was 16-way: 8-row stride = 544
// words = 0 mod 32 banks); frag reads stay at the structural minimum.
// (2) wave-uniform skip of fully-masked 16x16 subtiles in QK/exp and of
// fully-masked query-tiles in PV.
// ---------------------------------------------------------------------------
#define KSP 72    // Ks row stride (shorts)
#define VTP 136   // Vt row stride (shorts)
#define PSP 40    // Ps row stride (shorts)

__global__ __launch_bounds__(256) void swattn_mfma(const ushort* __restrict__ QKV,
                                                   ushort* __restrict__ O) {
    __shared__ __align__(16) ushort Ks[128 * KSP];      // 18432 B  [key][d]
    __shared__ __align__(16) ushort Vt[64 * VTP];       // 17408 B  [pi(d)][key]
    __shared__ __align__(16) ushort Ps[4 * 64 * PSP];   // 20480 B  per-wave [q][key32]
    __shared__ __align__(16) float lW[256];             // 1024 B

    const int j = blockIdx.x, h = blockIdx.y, b = blockIdx.z;
    const int tid = threadIdx.x;
    const int w = tid >> 6, l = tid & 63;
    const int quad = l >> 4, lc = l & 15;

    const size_t base = (size_t)b * S_LEN * NQKV + (size_t)h * DH;
    const ushort* Qp = QKV + base;               // row stride NQKV
    const ushort* Kp = QKV + base + DMODEL;
    const ushort* Vp = QKV + base + 2 * DMODEL;

    short8 qf[4][2];
#pragma unroll
    for (int nq = 0; nq < 4; ++nq)
#pragma unroll
        for (int kk = 0; kk < 2; ++kk)
            qf[nq][kk] = *(const short8*)(Qp +
                (size_t)(j * 256 + w * 64 + nq * 16 + lc) * NQKV + kk * 32 + quad * 8);

    floatx4 o[4][4] = {};
    float lsum[4] = {0.f, 0.f, 0.f, 0.f};

    const float sscale = 0.18033688011112042f;  // log2(e)/sqrt(64)
    const float M0 = 2.0f;                      // fixed shift (exact: shift-invariance)
    const int qlo = w * 64, qhi = w * 64 + 63;

    for (int c = 0; c < 4; ++c) {
        const int kg0 = (j - 1) * 256 + c * 128;
        if (kg0 < 0) continue;
        __syncthreads();
#pragma unroll
        for (int i = 0; i < 4; ++i) {
            int cc = i * 256 + tid, key = cc >> 3, seg = cc & 7;
            *(short8*)&Ks[key * KSP + seg * 8] =
                *(const short8*)(Kp + (size_t)(kg0 + key) * NQKV + seg * 8);
            short8 vv = *(const short8*)(Vp + (size_t)(kg0 + key) * NQKV + seg * 8);
#pragma unroll
            for (int e = 0; e < 8; ++e)
                Vt[(e * 8 + seg) * VTP + key] = (ushort)vv[e];  // pi(seg*8+e)=e*8+seg
        }
        __syncthreads();

        const int krel0 = c * 128 - 256;
#pragma unroll
        for (int g = 0; g < 4; ++g) {
            const int k0 = krel0 + g * 32;
            if (k0 > qhi || k0 + 31 < qlo - 255) continue;

            // S^T = K·Q^T : D[key][q], with fully-masked-subtile skip
            floatx4 st[2][4];
            const floatx4 zero = {};
#pragma unroll
            for (int kt = 0; kt < 2; ++kt) {
                short8 kf0 = *(const short8*)&Ks[(g * 32 + kt * 16 + lc) * KSP + quad * 8];
                short8 kf1 = *(const short8*)&Ks[(g * 32 + kt * 16 + lc) * KSP + 32 + quad * 8];
#pragma unroll
                for (int nq = 0; nq < 4; ++nq) {
                    int kmin = k0 + kt * 16, qmin = qlo + nq * 16;
                    if (kmin > qmin + 15 || kmin + 15 + 255 < qmin) {  // uniform
                        st[kt][nq] = zero;
                        continue;
                    }
                    st[kt][nq] = __builtin_amdgcn_mfma_f32_16x16x32_bf16(kf0, qf[nq][0], zero, 0, 0, 0);
                    st[kt][nq] = __builtin_amdgcn_mfma_f32_16x16x32_bf16(kf1, qf[nq][1], st[kt][nq], 0, 0, 0);
                }
            }
#pragma unroll
            for (int kt = 0; kt < 2; ++kt)
#pragma unroll
                for (int nq = 0; nq < 4; ++nq) {
                    sh4 pv;
                    int kmin = k0 + kt * 16, qmin = qlo + nq * 16;
                    if (kmin > qmin + 15 || kmin + 15 + 255 < qmin) {  // uniform
                        pv[0] = pv[1] = pv[2] = pv[3] = 0;
                    } else {
#pragma unroll
                        for (int r = 0; r < 4; ++r) {
                            int krel = kmin + quad * 4 + r;  // C row = key
                            int qrel = qmin + lc;            // C col = q
                            bool valid = (krel <= qrel) && (krel + 255 >= qrel);
                            float p = valid ? exp2f(st[kt][nq][r] * sscale - M0) : 0.f;
                            lsum[nq] += p;
                            pv[r] = (short)f2bf(p);
                        }
                    }
                    *(sh4*)&Ps[w * 64 * PSP + (nq * 16 + lc) * PSP + kt * 16 + quad * 4] = pv;
                }
            __threadfence_block();

            // O += P·V : A=P[q][key] from Ps, B=V^T[d][key] from Vt (pi rows)
            short8 vf[4];
#pragma unroll
            for (int nd = 0; nd < 4; ++nd) {
                int prow = (lc & 7) * 8 + nd * 2 + (lc >> 3);  // pi(nd*16+lc)
                vf[nd] = *(const short8*)&Vt[prow * VTP + g * 32 + quad * 8];
            }
#pragma unroll
            for (int mq = 0; mq < 4; ++mq) {
                int qmin = qlo + mq * 16;
                if (k0 > qmin + 15 || k0 + 31 + 255 < qmin) continue;  // uniform
                short8 pf = *(const short8*)&Ps[w * 64 * PSP + (mq * 16 + lc) * PSP + quad * 8];
#pragma unroll
                for (int nd = 0; nd < 4; ++nd)
                    o[mq][nd] = __builtin_amdgcn_mfma_f32_16x16x32_bf16(pf, vf[nd], o[mq][nd], 0, 0, 0);
            }
            __threadfence_block();
        }
    }

#pragma unroll
    for (int nq = 0; nq < 4; ++nq) {
        lsum[nq] += __shfl_xor(lsum[nq], 16);
        lsum[nq] += __shfl_xor(lsum[nq], 32);
    }
    if (l < 16) {
#pragma unroll
        for (int nq = 0; nq < 4; ++nq) lW[w * 64 + nq * 16 + l] = lsum[nq];
    }
    __threadfence_block();
#pragma unroll
    for (int mq = 0; mq < 4; ++mq) {
        floatx4 lv = *(const floatx4*)&lW[w * 64 + mq * 16 + quad * 4];
#pragma unroll
        for (int r = 0; r < 4; ++r) {
            float inv = 1.f / lv[r];
            int token = j * 256 + w * 64 + mq * 16 + quad * 4 + r;
#pragma unroll
            for (int nd = 0; nd < 4; ++nd)
                O[(size_t)b * S_LEN * DMODEL + (size_t)token * DMODEL + h * DH + nd * 16 + lc] =
                    f2bf(o[mq][nd][r] * inv);
        }
    }
}

// ---------------------------------------------------------------------------
extern "C" void kernel_launch(void* const* d_in, const int* in_sizes, int n_in,
                              void* d_out, int out_size, void* d_ws, size_t ws_size,
                              hipStream_t stream) {
    const float* x  = (const float*)d_in[0];
    const float* wq = (const float*)d_in[1];
    const float* wk = (const float*)d_in[2];
    const float* wv = (const float*)d_in[3];
    const float* wo = (const float*)d_in[4];
    float* out = (float*)d_out;

    const int D = DMODEL;
    const int M = in_sizes[0] / D;  // B*S = 8192
    const int Bb = M / S_LEN;       // 2

    ushort* xb   = (ushort*)d_ws;
    ushort* W3b  = xb + (size_t)M * D;
    ushort* wob  = W3b + (size_t)NQKV * D;
    ushort* QKVb = wob + (size_t)D * D;
    ushort* Ob   = xb;  // overlay: xb dead after QKV GEMM

    const int nx8 = M * D / 8, nw8 = D * D / 8;
    const int ntot = nx8 + 4 * nw8;
    cvt_all<<<dim3((ntot + 255) / 256), dim3(256), 0, stream>>>(
        x, wq, wk, wv, wo, xb, W3b, wob, nx8, nw8);

    // Fused QKV projection: [M,3072] = xb @ W3b^T  (wide-tile GEMM)
    gemm_wide<false><<<dim3(NQKV / 256, M / 128), dim3(256), 0, stream>>>(
        xb, W3b, QKVb, M, NQKV, D);

    swattn_mfma<<<dim3(S_LEN / WIN, NH, Bb), dim3(256), 0, stream>>>(QKVb, Ob);

    // Output projection: out[M,1024] = Ob @ wob^T (fp32 out)
    gemm_bf16<true><<<dim3(D / 128, M / 128), dim3(256), 0, stream>>>(
        Ob, wob, out, M, D, D);
}

// Round 9
// 234.080 us; speedup vs baseline: 1.0532x; 1.0532x over previous
//
#include <hip/hip_runtime.h>

// Problem constants (match reference)
#define S_LEN 4096
#define DMODEL 1024
#define NH 16
#define DH 64
#define WIN 256
#define NQKV 3072  // fused QKV output width

typedef __attribute__((ext_vector_type(8))) short short8;
typedef __attribute__((ext_vector_type(4))) short sh4;
typedef __attribute__((ext_vector_type(4))) float floatx4;

__device__ __forceinline__ ushort f2bf(float f) {
    union { float f; unsigned int i; } x;
    x.f = f;
    unsigned int r = x.i + 0x7FFFu + ((x.i >> 16) & 1u);  // RNE
    return (ushort)(r >> 16);
}

// ---------------------------------------------------------------------------
// Fused fp32 -> bf16 convert for x, wq, wk, wv, wo in ONE dispatch.
// ---------------------------------------------------------------------------
__global__ __launch_bounds__(256) void cvt_all(const float* __restrict__ x,
                                               const float* __restrict__ wq,
                                               const float* __restrict__ wk,
                                               const float* __restrict__ wv,
                                               const float* __restrict__ wo,
                                               ushort* __restrict__ xb,
                                               ushort* __restrict__ W3b,
                                               ushort* __restrict__ wob,
                                               int nx8, int nw8) {
    int i = blockIdx.x * 256 + threadIdx.x;
    const float* src;
    ushort* dst;
    if (i < nx8) {
        src = x + (size_t)i * 8;            dst = xb + (size_t)i * 8;
    } else {
        int j = i - nx8;
        int which = j / nw8, r = j - which * nw8;
        if (which >= 4) return;
        const float* w4[4] = {wq, wk, wv, wo};
        src = w4[which] + (size_t)r * 8;
        dst = (which == 3 ? wob : W3b + (size_t)which * nw8 * 8) + (size_t)r * 8;
    }
    floatx4 f0 = *(const floatx4*)src;
    floatx4 f1 = *(const floatx4*)(src + 4);
    short8 v;
#pragma unroll
    for (int e = 0; e < 4; ++e) v[e] = (short)f2bf(f0[e]);
#pragma unroll
    for (int e = 0; e < 4; ++e) v[4 + e] = (short)f2bf(f1[e]);
    *(short8*)dst = v;
}

// ---------------------------------------------------------------------------
// bf16 GEMM, 128x128 tile, BK=32 (m97 structure) — output projection.
// ---------------------------------------------------------------------------
template <bool OUTF32>
__global__ __launch_bounds__(256) void gemm_bf16(const ushort* __restrict__ A,
                                                 const ushort* __restrict__ W,
                                                 void* __restrict__ Cout,
                                                 int M, int N, int K) {
    __shared__ __align__(16) ushort As[128 * 32];  // 8 KB
    __shared__ __align__(16) ushort Ws[128 * 32];

    const int tid = threadIdx.x;
    const int w = tid >> 6, l = tid & 63;
    const int bm0 = blockIdx.y * 128, bn0 = blockIdx.x * 128;
    const int wm = (w >> 1) * 64, wn = (w & 1) * 64;
    const int lm = l & 15, quad = l >> 4;

    floatx4 acc[4][4] = {};

    const int row0 = tid >> 2, col0 = (tid & 3) * 8;
    const ushort* a0 = A + (size_t)(bm0 + row0) * K + col0;
    const ushort* a1 = A + (size_t)(bm0 + row0 + 64) * K + col0;
    const ushort* w0 = W + (size_t)(bn0 + row0) * K + col0;
    const ushort* w1 = W + (size_t)(bn0 + row0 + 64) * K + col0;

    for (int k0 = 0; k0 < K; k0 += 32) {
        __builtin_amdgcn_global_load_lds(
            (const __attribute__((address_space(1))) void*)(a0 + k0),
            (__attribute__((address_space(3))) void*)(As + tid * 8), 16, 0, 0);
        __builtin_amdgcn_global_load_lds(
            (const __attribute__((address_space(1))) void*)(a1 + k0),
            (__attribute__((address_space(3))) void*)(As + 2048 + tid * 8), 16, 0, 0);
        __builtin_amdgcn_global_load_lds(
            (const __attribute__((address_space(1))) void*)(w0 + k0),
            (__attribute__((address_space(3))) void*)(Ws + tid * 8), 16, 0, 0);
        __builtin_amdgcn_global_load_lds(
            (const __attribute__((address_space(1))) void*)(w1 + k0),
            (__attribute__((address_space(3))) void*)(Ws + 2048 + tid * 8), 16, 0, 0);
        __syncthreads();

        short8 af[4], wf[4];
#pragma unroll
        for (int mi = 0; mi < 4; ++mi)
            af[mi] = *(const short8*)&As[(wm + mi * 16 + lm) * 32 + quad * 8];
#pragma unroll
        for (int ni = 0; ni < 4; ++ni)
            wf[ni] = *(const short8*)&Ws[(wn + ni * 16 + lm) * 32 + quad * 8];
#pragma unroll
        for (int mi = 0; mi < 4; ++mi)
#pragma unroll
            for (int ni = 0; ni < 4; ++ni)
                acc[mi][ni] = __builtin_amdgcn_mfma_f32_16x16x32_bf16(
                    af[mi], wf[ni], acc[mi][ni], 0, 0, 0);
        __syncthreads();
    }

#pragma unroll
    for (int mi = 0; mi < 4; ++mi)
#pragma unroll
        for (int ni = 0; ni < 4; ++ni)
#pragma unroll
            for (int r = 0; r < 4; ++r) {
                int row = bm0 + wm + mi * 16 + quad * 4 + r;
                int col = bn0 + wn + ni * 16 + lm;
                if (OUTF32)
                    ((float*)Cout)[(size_t)row * N + col] = acc[mi][ni][r];
                else
                    ((ushort*)Cout)[(size_t)row * N + col] = f2bf(acc[mi][ni][r]);
            }
}

// ---------------------------------------------------------------------------
// QKV GEMM: 128x256 block, 64x128 wave tile, BK=64 — HALF the barrier drains
// of BK=32 (the measured structural stall), 64 MFMA per wave per barrier.
// LDS rows are 128 B; global-source XOR swizzle seg' = seg ^ (row&7) keeps
// frag reads at the structural bank minimum while staging stays coalesced.
// ---------------------------------------------------------------------------
template <bool OUTF32>
__global__ __launch_bounds__(256, 2) void gemm_qkv(const ushort* __restrict__ A,
                                                   const ushort* __restrict__ W,
                                                   void* __restrict__ Cout,
                                                   int M, int N, int K) {
    __shared__ __align__(16) ushort As[128 * 64];  // 16 KB
    __shared__ __align__(16) ushort Ws[256 * 64];  // 32 KB

    const int tid = threadIdx.x;
    const int w = tid >> 6, l = tid & 63;
    const int bm0 = blockIdx.y * 128, bn0 = blockIdx.x * 256;
    const int wm = (w >> 1) * 64, wn = (w & 1) * 128;
    const int lm = l & 15, quad = l >> 4;

    floatx4 acc[4][8] = {};

    // Staging: chunk c (16 B): row = c>>3, pos = c&7, global seg = pos^(row&7).
    // A: 1024 chunks (4/thread), W: 2048 chunks (8/thread).
    int arow[4], acol[4];
#pragma unroll
    for (int p = 0; p < 4; ++p) {
        int c = p * 256 + tid;
        arow[p] = c >> 3;
        acol[p] = (((c & 7) ^ (arow[p] & 7))) * 8;
    }
    int wrow[8], wcol[8];
#pragma unroll
    for (int p = 0; p < 8; ++p) {
        int c = p * 256 + tid;
        wrow[p] = c >> 3;
        wcol[p] = (((c & 7) ^ (wrow[p] & 7))) * 8;
    }

    for (int k0 = 0; k0 < K; k0 += 64) {
#pragma unroll
        for (int p = 0; p < 4; ++p)
            __builtin_amdgcn_global_load_lds(
                (const __attribute__((address_space(1))) void*)
                    (A + (size_t)(bm0 + arow[p]) * K + k0 + acol[p]),
                (__attribute__((address_space(3))) void*)(As + p * 2048 + tid * 8),
                16, 0, 0);
#pragma unroll
        for (int p = 0; p < 8; ++p)
            __builtin_amdgcn_global_load_lds(
                (const __attribute__((address_space(1))) void*)
                    (W + (size_t)(bn0 + wrow[p]) * K + k0 + wcol[p]),
                (__attribute__((address_space(3))) void*)(Ws + p * 2048 + tid * 8),
                16, 0, 0);
        __syncthreads();  // drains vmcnt(0): staging complete

#pragma unroll
        for (int kk = 0; kk < 2; ++kk) {
            const int sseg = ((kk * 4 + quad) ^ (lm & 7)) * 8;
            short8 af[4], wf[8];
#pragma unroll
            for (int mi = 0; mi < 4; ++mi)
                af[mi] = *(const short8*)&As[(wm + mi * 16 + lm) * 64 + sseg];
#pragma unroll
            for (int ni = 0; ni < 8; ++ni)
                wf[ni] = *(const short8*)&Ws[(wn + ni * 16 + lm) * 64 + sseg];
#pragma unroll
            for (int mi = 0; mi < 4; ++mi)
#pragma unroll
                for (int ni = 0; ni < 8; ++ni)
                    acc[mi][ni] = __builtin_amdgcn_mfma_f32_16x16x32_bf16(
                        af[mi], wf[ni], acc[mi][ni], 0, 0, 0);
        }
        __syncthreads();  // frag reads done before next staging overwrites
    }

#pragma unroll
    for (int mi = 0; mi < 4; ++mi)
#pragma unroll
        for (int ni = 0; ni < 8; ++ni)
#pragma unroll
            for (int r = 0; r < 4; ++r) {
                int row = bm0 + wm + mi * 16 + quad * 4 + r;
                int col = bn0 + wn + ni * 16 + lm;
                if (OUTF32)
                    ((float*)Cout)[(size_t)row * N + col] = acc[mi][ni][r];
                else
                    ((ushort*)Cout)[(size_t)row * N + col] = f2bf(acc[mi][ni][r]);
            }
}

// ---------------------------------------------------------------------------
// MFMA sliding-window attention over fused QKV layout [M][3072].
// R9: Ps double-buffered (second per-group fence deleted); softmax split into
// interior (no mask eval) vs boundary subtiles. Vt pi-permuted rows (R8).
// ---------------------------------------------------------------------------
#define KSP 72    // Ks row stride (shorts)
#define VTP 136   // Vt row stride (shorts)
#define PSP 40    // Ps row stride (shorts)

__global__ __launch_bounds__(256) void swattn_mfma(const ushort* __restrict__ QKV,
                                                   ushort* __restrict__ O) {
    __shared__ __align__(16) ushort Ks[128 * KSP];        // 18432 B  [key][d]
    __shared__ __align__(16) ushort Vt[64 * VTP];         // 17408 B  [pi(d)][key]
    __shared__ __align__(16) ushort Ps[2][4 * 64 * PSP];  // 40960 B  dbuf per-wave [q][key32]
    __shared__ __align__(16) float lW[256];               // 1024 B

    const int j = blockIdx.x, h = blockIdx.y, b = blockIdx.z;
    const int tid = threadIdx.x;
    const int w = tid >> 6, l = tid & 63;
    const int quad = l >> 4, lc = l & 15;

    const size_t base = (size_t)b * S_LEN * NQKV + (size_t)h * DH;
    const ushort* Qp = QKV + base;               // row stride NQKV
    const ushort* Kp = QKV + base + DMODEL;
    const ushort* Vp = QKV + base + 2 * DMODEL;

    short8 qf[4][2];
#pragma unroll
    for (int nq = 0; nq < 4; ++nq)
#pragma unroll
        for (int kk = 0; kk < 2; ++kk)
            qf[nq][kk] = *(const short8*)(Qp +
                (size_t)(j * 256 + w * 64 + nq * 16 + lc) * NQKV + kk * 32 + quad * 8);

    floatx4 o[4][4] = {};
    float lsum[4] = {0.f, 0.f, 0.f, 0.f};

    const float sscale = 0.18033688011112042f;  // log2(e)/sqrt(64)
    const float M0 = 2.0f;                      // fixed shift (exact: shift-invariance)
    const int qlo = w * 64, qhi = w * 64 + 63;

    for (int c = 0; c < 4; ++c) {
        const int kg0 = (j - 1) * 256 + c * 128;
        if (kg0 < 0) continue;
        __syncthreads();
#pragma unroll
        for (int i = 0; i < 4; ++i) {
            int cc = i * 256 + tid, key = cc >> 3, seg = cc & 7;
            *(short8*)&Ks[key * KSP + seg * 8] =
                *(const short8*)(Kp + (size_t)(kg0 + key) * NQKV + seg * 8);
            short8 vv = *(const short8*)(Vp + (size_t)(kg0 + key) * NQKV + seg * 8);
#pragma unroll
            for (int e = 0; e < 8; ++e)
                Vt[(e * 8 + seg) * VTP + key] = (ushort)vv[e];  // pi(seg*8+e)=e*8+seg
        }
        __syncthreads();

        const int krel0 = c * 128 - 256;
#pragma unroll
        for (int g = 0; g < 4; ++g) {
            const int k0 = krel0 + g * 32;
            if (k0 > qhi || k0 + 31 < qlo - 255) continue;
            ushort* Pw = &Ps[g & 1][w * 64 * PSP];

            // S^T = K·Q^T : D[key][q], with fully-masked-subtile skip
            floatx4 st[2][4];
            const floatx4 zero = {};
#pragma unroll
            for (int kt = 0; kt < 2; ++kt) {
                short8 kf0 = *(const short8*)&Ks[(g * 32 + kt * 16 + lc) * KSP + quad * 8];
                short8 kf1 = *(const short8*)&Ks[(g * 32 + kt * 16 + lc) * KSP + 32 + quad * 8];
#pragma unroll
                for (int nq = 0; nq < 4; ++nq) {
                    int kmin = k0 + kt * 16, qmin = qlo + nq * 16;
                    if (kmin > qmin + 15 || kmin + 270 < qmin) {  // fully masked
                        st[kt][nq] = zero;
                        continue;
                    }
                    st[kt][nq] = __builtin_amdgcn_mfma_f32_16x16x32_bf16(kf0, qf[nq][0], zero, 0, 0, 0);
                    st[kt][nq] = __builtin_amdgcn_mfma_f32_16x16x32_bf16(kf1, qf[nq][1], st[kt][nq], 0, 0, 0);
                }
            }
#pragma unroll
            for (int kt = 0; kt < 2; ++kt)
#pragma unroll
                for (int nq = 0; nq < 4; ++nq) {
                    sh4 pv;
                    int kmin = k0 + kt * 16, qmin = qlo + nq * 16;
                    if (kmin > qmin + 15 || kmin + 270 < qmin) {           // fully masked
                        pv[0] = pv[1] = pv[2] = pv[3] = 0;
                    } else if (kmin + 15 <= qmin && kmin + 240 >= qmin) {  // interior: no mask
#pragma unroll
                        for (int r = 0; r < 4; ++r) {
                            float p = exp2f(st[kt][nq][r] * sscale - M0);
                            lsum[nq] += p;
                            pv[r] = (short)f2bf(p);
                        }
                    } else {                                               // boundary
#pragma unroll
                        for (int r = 0; r < 4; ++r) {
                            int krel = kmin + quad * 4 + r;  // C row = key
                            int qrel = qmin + lc;            // C col = q
                            bool valid = (krel <= qrel) && (krel + 255 >= qrel);
                            float p = valid ? exp2f(st[kt][nq][r] * sscale - M0) : 0.f;
                            lsum[nq] += p;
                            pv[r] = (short)f2bf(p);
                        }
                    }
                    *(sh4*)&Pw[(nq * 16 + lc) * PSP + kt * 16 + quad * 4] = pv;
                }
            __threadfence_block();  // P writes visible before lane-crossed reads

            // O += P·V : A=P[q][key] from Ps, B=V^T[d][key] from Vt (pi rows)
            short8 vf[4];
#pragma unroll
            for (int nd = 0; nd < 4; ++nd) {
                int prow = (lc & 7) * 8 + nd * 2 + (lc >> 3);  // pi(nd*16+lc)
                vf[nd] = *(const short8*)&Vt[prow * VTP + g * 32 + quad * 8];
            }
#pragma unroll
            for (int mq = 0; mq < 4; ++mq) {
                int qmin = qlo + mq * 16;
                if (k0 > qmin + 15 || k0 + 286 < qmin) continue;  // group fully masked
                short8 pf = *(const short8*)&Pw[(mq * 16 + lc) * PSP + quad * 8];
#pragma unroll
                for (int nd = 0; nd < 4; ++nd)
                    o[mq][nd] = __builtin_amdgcn_mfma_f32_16x16x32_bf16(pf, vf[nd], o[mq][nd], 0, 0, 0);
            }
            // no trailing fence: next group writes the OTHER Ps buffer; the
            // group-after-next is separated by the next group's fence.
        }
    }

#pragma unroll
    for (int nq = 0; nq < 4; ++nq) {
        lsum[nq] += __shfl_xor(lsum[nq], 16);
        lsum[nq] += __shfl_xor(lsum[nq], 32);
    }
    if (l < 16) {
#pragma unroll
        for (int nq = 0; nq < 4; ++nq) lW[w * 64 + nq * 16 + l] = lsum[nq];
    }
    __threadfence_block();
#pragma unroll
    for (int mq = 0; mq < 4; ++mq) {
        floatx4 lv = *(const floatx4*)&lW[w * 64 + mq * 16 + quad * 4];
#pragma unroll
        for (int r = 0; r < 4; ++r) {
            float inv = 1.f / lv[r];
            int token = j * 256 + w * 64 + mq * 16 + quad * 4 + r;
#pragma unroll
            for (int nd = 0; nd < 4; ++nd)
                O[(size_t)b * S_LEN * DMODEL + (size_t)token * DMODEL + h * DH + nd * 16 + lc] =
                    f2bf(o[mq][nd][r] * inv);
        }
    }
}

// ---------------------------------------------------------------------------
extern "C" void kernel_launch(void* const* d_in, const int* in_sizes, int n_in,
                              void* d_out, int out_size, void* d_ws, size_t ws_size,
                              hipStream_t stream) {
    const float* x  = (const float*)d_in[0];
    const float* wq = (const float*)d_in[1];
    const float* wk = (const float*)d_in[2];
    const float* wv = (const float*)d_in[3];
    const float* wo = (const float*)d_in[4];
    float* out = (float*)d_out;

    const int D = DMODEL;
    const int M = in_sizes[0] / D;  // B*S = 8192
    const int Bb = M / S_LEN;       // 2

    ushort* xb   = (ushort*)d_ws;
    ushort* W3b  = xb + (size_t)M * D;
    ushort* wob  = W3b + (size_t)NQKV * D;
    ushort* QKVb = wob + (size_t)D * D;
    ushort* Ob   = xb;  // overlay: xb dead after QKV GEMM

    const int nx8 = M * D / 8, nw8 = D * D / 8;
    const int ntot = nx8 + 4 * nw8;
    cvt_all<<<dim3((ntot + 255) / 256), dim3(256), 0, stream>>>(
        x, wq, wk, wv, wo, xb, W3b, wob, nx8, nw8);

    // Fused QKV projection: [M,3072] = xb @ W3b^T  (BK=64 wide-tile GEMM)
    gemm_qkv<false><<<dim3(NQKV / 256, M / 128), dim3(256), 0, stream>>>(
        xb, W3b, QKVb, M, NQKV, D);

    swattn_mfma<<<dim3(S_LEN / WIN, NH, Bb), dim3(256), 0, stream>>>(QKVb, Ob);

    // Output projection: out[M,1024] = Ob @ wob^T (fp32 out)
    gemm_bf16<true><<<dim3(D / 128, M / 128), dim3(256), 0, stream>>>(
        Ob, wob, out, M, D, D);
}